// Round 7
// baseline (123.466 us; speedup 1.0000x reference)
//
#include <hip/hip_runtime.h>

#define NF    50000
#define PADP  50001
#define KN    9
#define KTOT  2304
#define NCHUNK 782
#define NT    72          // 2304/32 K-tiles
#define TSZ   16384       // tile: A 128x64B (8KB) + B 128x64B (8KB)
#define RSZ   49152       // ring-3
#define NBLK  782         // 391 M-blocks x 2 N-blocks

// ---- ws layout (bytes) ----
#define WT_OFF   0u          // 256*2304*2 = 1179648
#define FLAG_OFF 1179648u
#define CNT_OFF  1179904u    // 782*4
#define PADX_OFF 1183744u    // 50001*256*2

typedef float f32x4 __attribute__((ext_vector_type(4)));
typedef __bf16 bf16x8 __attribute__((ext_vector_type(8)));

typedef const __attribute__((address_space(1))) unsigned int* gas_t;
typedef __attribute__((address_space(3))) unsigned int* las_t;

static __device__ __forceinline__ void gll16(const void* g, void* l) {
  __builtin_amdgcn_global_load_lds((gas_t)g, (las_t)l, 16, 0, 0);
}

static __device__ __forceinline__ unsigned short f2bf(float f) {
  unsigned int u = __builtin_bit_cast(unsigned int, f);
  u = u + 0x7fffu + ((u >> 16) & 1u);      // RNE
  return (unsigned short)(u >> 16);
}

// ---------- preprocessing ----------

// fused: weight demod+transpose (blocks 0..255) | pad chunk counts + flag (blocks 256..451)
__global__ void k_prep(const float* __restrict__ w, unsigned short* __restrict__ wt,
                       const unsigned char* __restrict__ pad, int* __restrict__ cnt,
                       const unsigned int* __restrict__ raw, int* __restrict__ flag) {
  if (blockIdx.x < 256) {
    int o = blockIdx.x;
    int i = threadIdx.x;
    const float* wr = w + (o * 256 + i) * 9;
    float wv[9];
    float s = 0.f;
#pragma unroll
    for (int k = 0; k < 9; ++k) { wv[k] = wr[k]; s += wv[k] * wv[k]; }
#pragma unroll
    for (int d = 32; d >= 1; d >>= 1) s += __shfl_xor(s, d);
    __shared__ float red[4];
    if ((i & 63) == 0) red[i >> 6] = s;
    __syncthreads();
    float dc = rsqrtf(red[0] + red[1] + red[2] + red[3] + 1e-8f);
#pragma unroll
    for (int k = 0; k < 9; ++k)
      wt[o * KTOT + k * 256 + i] = f2bf(wv[k] * dc);
  } else {
    int cb = blockIdx.x - 256;
    int t = cb * 256 + threadIdx.x;
    bool ip = (t < PADP) ? (pad[t] != 0) : true;
    unsigned long long m = __ballot(ip);
    int c = t >> 6;
    if ((threadIdx.x & 63) == 0 && c < NCHUNK) cnt[c] = __popcll(m);
    if (cb == 0 && threadIdx.x < 64) {
      unsigned int v = raw[threadIdx.x * 2 + 1];
      unsigned long long nz = __ballot(v != 0u);
      if (threadIdx.x == 0) flag[0] = (nz == 0ull) ? 1 : 0;
    }
  }
}

// one block per 64-row chunk: prefix over cnt -> ranks -> bf16 conversion
__global__ __launch_bounds__(256) void k_rankpadx(
    const float* __restrict__ x, const unsigned char* __restrict__ pad,
    const int* __restrict__ cnt, unsigned short* __restrict__ padx) {
  const int c = blockIdx.x;
  const int tid = threadIdx.x, w = tid >> 6, lane = tid & 63;
  int s = 0;
  for (int i = tid; i < c; i += 256) s += cnt[i];
#pragma unroll
  for (int d = 32; d >= 1; d >>= 1) s += __shfl_xor(s, d);
  __shared__ int red[4];
  __shared__ int rnk[64];
  if (lane == 0) red[w] = s;
  __syncthreads();
  const int S = red[0] + red[1] + red[2] + red[3];
  if (w == 0) {
    int p = c * 64 + lane;
    bool ip = (p < PADP) ? (pad[p] != 0) : true;
    unsigned long long m = __ballot(ip);
    int before = __popcll(m & ((1ull << lane) - 1ull));
    rnk[lane] = ip ? -1 : (p - (S + before));
  }
  __syncthreads();
  const int col = lane * 4;
#pragma unroll
  for (int i = 0; i < 16; ++i) {
    int rl = i * 4 + w;
    int pp = c * 64 + rl;
    if (pp >= PADP) continue;
    int rr = rnk[rl];
    ushort4 ov;
    if (rr < 0) { ov.x = 0; ov.y = 0; ov.z = 0; ov.w = 0; }
    else {
      const float4 v = *(const float4*)(x + rr * 256 + col);
      ov.x = f2bf(v.x); ov.y = f2bf(v.y); ov.z = f2bf(v.z); ov.w = f2bf(v.w);
    }
    *(ushort4*)(padx + pp * 256 + col) = ov;
  }
}

// ---------- main gathered GEMM ----------
// BM=128 x BN=128 x BK=32, 256 thr (4 waves, 2M x 2N), wave-tile 64x64 (4x4).
// LDS: ring-3 x 16KB + idx cache 4608B = 53760B -> 3 blocks/CU.
// Per iter t: frag-read(t+1) [alt reg set] || stage(t+3, 4 gll16, slot t%3)
//             -> 16 MFMA(t) -> vmcnt(4)+lgkmcnt(0) -> ONE s_barrier.
// Staging lane-linear dest (tid*16), swizzle on source: slot s of row r holds
// global slot s ^ ((r>>1)&3); fragment reads use the matching XOR.
__global__ __launch_bounds__(256, 3) void k_main(
    const unsigned short* __restrict__ padx,   // [50001][256] bf16
    const unsigned short* __restrict__ wt,     // [256][2304] bf16
    const void* __restrict__ nbr,              // [50000][9] int64 or int32
    const int* __restrict__ flag,
    const float* __restrict__ bias,            // [256]
    float* __restrict__ out) {                 // [50000][256] f32
  __shared__ __align__(16) unsigned char sm[53760];
  const int tid = threadIdx.x;
  const int wv = tid >> 6, lane = tid & 63;
  const int mblk = blockIdx.x >> 1, nblk = blockIdx.x & 1;
  const int m0 = mblk * 128, n0 = nblk * 128;
  int* idx_lds = (int*)(sm + RSZ);             // 128*9 ints

  const int q = lane & 15, hi = lane >> 4;
  const int wm = wv >> 1, wn = wv & 1;

  // bias preload (drained by the syncthreads below)
  float bv[4];
#pragma unroll
  for (int ni = 0; ni < 4; ++ni) bv[ni] = bias[n0 + wn * 64 + ni * 16 + q];

  // idx cache: faces m0..m0+127, 9 neighbors
  const bool f64 = (flag[0] != 0);
  const long long* n64 = (const long long*)nbr;
  const int* n32 = (const int*)nbr;
  for (int e = tid; e < 128 * 9; e += 256) {
    int f = m0 + e / 9;
    if (f >= NF) f = NF - 1;
    int k = e - (e / 9) * 9;
    idx_lds[e] = f64 ? (int)n64[f * KN + k] : n32[f * KN + k];
  }
  __syncthreads();

  // ---- staging setup: each gll16 = 64 rows x 64B? no: 256 thr x 16B = 4KB = 64 rows ----
  const int rA = tid >> 2;                                  // 0..63 (4 lanes/row)
  const int srcsl = ((tid & 3) ^ ((tid >> 3) & 3)) * 8;     // swizzled src slot (elems)
  const int aD0 = tid * 16;                                 // A rows 0..63
  const int aD1 = 4096 + tid * 16;                          // A rows 64..127
  const int bD0 = 8192 + tid * 16;                          // B rows 0..63
  const int bD1 = 12288 + tid * 16;                         // B rows 64..127
  const unsigned short* wtb0 = wt + (n0 + rA) * KTOT + srcsl;
  const unsigned short* wtb1 = wt + (n0 + 64 + rA) * KTOT + srcsl;

  // ---- fragment read offsets (bytes within one ring slot) ----
  const int slotb = (hi ^ ((q >> 1) & 3)) * 16;
  int aoff[4], boff[4];
#pragma unroll
  for (int mi = 0; mi < 4; ++mi) aoff[mi] = (wm * 64 + mi * 16 + q) * 64 + slotb;
#pragma unroll
  for (int ni = 0; ni < 4; ++ni) boff[ni] = 8192 + (wn * 64 + ni * 16 + q) * 64 + slotb;

  f32x4 acc[4][4];
#pragma unroll
  for (int a = 0; a < 4; ++a)
#pragma unroll
    for (int b = 0; b < 4; ++b) {
      acc[a][b][0] = 0.f; acc[a][b][1] = 0.f; acc[a][b][2] = 0.f; acc[a][b][3] = 0.f;
    }

  // per-thread gather indices for the two A row-sets
  int pc0 = idx_lds[rA * 9 + 0], pc1 = idx_lds[(64 + rA) * 9 + 0];
  int pn0 = idx_lds[rA * 9 + 1], pn1 = idx_lds[(64 + rA) * 9 + 1];
  int pq0 = pn0, pq1 = pn1;

  // ---- prologue: stage tiles 0,1,2 (group 0) ----
#pragma unroll
  for (int u = 0; u < 3; ++u) {
    unsigned char* wb = sm + u * TSZ;
    gll16(padx + pc0 * 256 + u * 32 + srcsl, wb + aD0);
    gll16(padx + pc1 * 256 + u * 32 + srcsl, wb + aD1);
    gll16(wtb0 + u * 32, wb + bD0);
    gll16(wtb1 + u * 32, wb + bD1);
  }
  asm volatile("s_waitcnt vmcnt(4)" ::: "memory");   // tiles 0,1 resident
  __builtin_amdgcn_s_barrier();

  bf16x8 af0[4], bf0[4], af1[4], bf1[4];
#pragma unroll
  for (int mi = 0; mi < 4; ++mi) af0[mi] = *(const bf16x8*)(sm + aoff[mi]);
#pragma unroll
  for (int ni = 0; ni < 4; ++ni) bf0[ni] = *(const bf16x8*)(sm + boff[ni]);
  asm volatile("s_waitcnt lgkmcnt(0)" ::: "memory");
  __builtin_amdgcn_sched_barrier(0);
  __builtin_amdgcn_s_barrier();   // protects slot-0 readers from iter-0's stage

  int oR = TSZ;   // slot of tile t+1
  int oW = 0;     // slot being overwritten with tile t+3 (= slot t%3)

#define ITER(J, cA, cB, nA, nB) {                                          \
  const unsigned char* rb_ = sm + oR;                                      \
  _Pragma("unroll")                                                        \
  for (int mi = 0; mi < 4; ++mi) nA[mi] = *(const bf16x8*)(rb_ + aoff[mi]);\
  _Pragma("unroll")                                                        \
  for (int ni = 0; ni < 4; ++ni) nB[ni] = *(const bf16x8*)(rb_ + boff[ni]);\
  {                                                                        \
    const int u_ = g8 + (J) + 3;                                           \
    const bool real_ = (u_ < NT);                                          \
    const int c0_ = real_ ? (((J) + 3) & 7) * 32 : 224;                    \
    const int kg_ = (real_ ? u_ : NT - 1) * 32;                            \
    const int pA0_ = ((J) >= 5 && real_) ? pn0 : pc0;                      \
    const int pA1_ = ((J) >= 5 && real_) ? pn1 : pc1;                      \
    unsigned char* wb_ = sm + oW;                                          \
    gll16(padx + pA0_ * 256 + c0_ + srcsl, wb_ + aD0);                     \
    gll16(padx + pA1_ * 256 + c0_ + srcsl, wb_ + aD1);                     \
    gll16(wtb0 + kg_, wb_ + bD0);                                          \
    gll16(wtb1 + kg_, wb_ + bD1);                                          \
  }                                                                        \
  if ((J) == 0) {                                                          \
    const int gn_ = (g + 2 > 8) ? 8 : g + 2;                               \
    pq0 = idx_lds[rA * 9 + gn_];                                           \
    pq1 = idx_lds[(64 + rA) * 9 + gn_];                                    \
  }                                                                        \
  __builtin_amdgcn_sched_barrier(0);                                       \
  __builtin_amdgcn_s_setprio(1);                                           \
  _Pragma("unroll")                                                        \
  for (int mi = 0; mi < 4; ++mi)                                           \
    _Pragma("unroll")                                                      \
    for (int ni = 0; ni < 4; ++ni)                                         \
      acc[mi][ni] = __builtin_amdgcn_mfma_f32_16x16x32_bf16(               \
          cA[mi], cB[ni], acc[mi][ni], 0, 0, 0);                           \
  __builtin_amdgcn_s_setprio(0);                                           \
  __builtin_amdgcn_sched_barrier(0);                                       \
  asm volatile("s_waitcnt vmcnt(4)" ::: "memory");                         \
  asm volatile("s_waitcnt lgkmcnt(0)" ::: "memory");                       \
  __builtin_amdgcn_sched_barrier(0);                                       \
  __builtin_amdgcn_s_barrier();                                            \
  oR += TSZ; if (oR == RSZ) oR = 0;                                        \
  oW += TSZ; if (oW == RSZ) oW = 0;                                        \
}

#pragma unroll 1
  for (int g = 0; g < 9; ++g) {
    const int g8 = g * 8;
    ITER(0, af0, bf0, af1, bf1)
    ITER(1, af1, bf1, af0, bf0)
    ITER(2, af0, bf0, af1, bf1)
    ITER(3, af1, bf1, af0, bf0)
    ITER(4, af0, bf0, af1, bf1)
    ITER(5, af1, bf1, af0, bf0)
    ITER(6, af0, bf0, af1, bf1)
    ITER(7, af1, bf1, af0, bf0)
    pc0 = pn0; pc1 = pn1; pn0 = pq0; pn1 = pq1;
  }
#undef ITER
  asm volatile("s_waitcnt vmcnt(0)" ::: "memory");

  // ---- epilogue: bias + store (D: col = q, row = hi*4 + r) ----
#pragma unroll
  for (int ni = 0; ni < 4; ++ni) {
    const int col = n0 + wn * 64 + ni * 16 + q;
#pragma unroll
    for (int mi = 0; mi < 4; ++mi) {
#pragma unroll
      for (int rr = 0; rr < 4; ++rr) {
        const int row = m0 + wm * 64 + mi * 16 + hi * 4 + rr;
        if (row < NF) out[row * 256 + col] = acc[mi][ni][rr] + bv[ni];
      }
    }
  }
}

extern "C" void kernel_launch(void* const* d_in, const int* in_sizes, int n_in,
                              void* d_out, int out_size, void* d_ws, size_t ws_size,
                              hipStream_t stream) {
  const float* x = (const float*)d_in[0];
  const float* wfull = (const float*)d_in[1];
  const float* bias = (const float*)d_in[2];
  const void* nbr = d_in[3];
  const unsigned char* pad = (const unsigned char*)d_in[4];
  float* out = (float*)d_out;
  char* ws = (char*)d_ws;

  unsigned short* wt   = (unsigned short*)(ws + WT_OFF);
  int* flag            = (int*)(ws + FLAG_OFF);
  int* cnt             = (int*)(ws + CNT_OFF);
  unsigned short* padx = (unsigned short*)(ws + PADX_OFF);

  k_prep<<<452, 256, 0, stream>>>(wfull, wt, pad, cnt, (const unsigned int*)nbr, flag);
  k_rankpadx<<<NCHUNK, 256, 0, stream>>>(x, pad, cnt, padx);
  k_main<<<NBLK, 256, 0, stream>>>(padx, wt, nbr, flag, bias, out);
}